// Round 3
// baseline (60.262 us; speedup 1.0000x reference)
//
#include <hip/hip_runtime.h>

// HardEMQuantizer forward:
//   logits:     (B=8, T=2048, M*K=4096) fp32  -> N = B*T = 16384 rows, M=8 splits, K=512 codes
//   embeddings: (M=8, K=512, D=64) fp32
// Outputs (concatenated flat, all fp32):
//   [0 .. 8388608)        quantized        = gather of argmax embedding rows
//   [8388608 .. 16777216) quantized_stack  = same flat data
//   [16777216 .. 16908288) encoding_indices = argmax index as float
//
// Forward value of straight-through z is exactly one_hot(argmax), so the einsum
// collapses to a row gather; argmax(softmax(x)) == argmax(x).
//
// R3: 4 tasks per wave -> 8 independent 1 KiB logit loads in flight per wave,
// 4 interleaved reduce/gather chains (MLP/ILP vs R2's 2). Non-temporal
// streaming loads/stores; 4-lane coalesced index store.

#define MM 8
#define KK 512
#define DD 64

typedef float f32x4 __attribute__((ext_vector_type(4)));

__device__ inline void task_argmax(f32x4 a, f32x4 b, int lane, float& best, int& bidx) {
    int k0 = lane * 4;
    best = a.x; bidx = k0;
    if (a.y > best) { best = a.y; bidx = k0 + 1; }
    if (a.z > best) { best = a.z; bidx = k0 + 2; }
    if (a.w > best) { best = a.w; bidx = k0 + 3; }
    int k1 = 256 + lane * 4;
    if (b.x > best) { best = b.x; bidx = k1;     }
    if (b.y > best) { best = b.y; bidx = k1 + 1; }
    if (b.z > best) { best = b.z; bidx = k1 + 2; }
    if (b.w > best) { best = b.w; bidx = k1 + 3; }
}

__global__ __launch_bounds__(256) void hardem_fwd(
    const float* __restrict__ logits,   // (N*M, K) contiguous
    const float* __restrict__ emb,      // (M, K, D)
    float* __restrict__ out)
{
    const int wave = threadIdx.x >> 6;
    const int lane = threadIdx.x & 63;
    const int wid  = blockIdx.x * 4 + wave;
    const int t0   = wid * 4;           // four adjacent tasks per wave

    // 8 independent coalesced 1 KiB loads, all issued up front.
    const f32x4* s0 = (const f32x4*)(logits + (size_t)(t0 + 0) * KK);
    const f32x4* s1 = (const f32x4*)(logits + (size_t)(t0 + 1) * KK);
    const f32x4* s2 = (const f32x4*)(logits + (size_t)(t0 + 2) * KK);
    const f32x4* s3 = (const f32x4*)(logits + (size_t)(t0 + 3) * KK);
    f32x4 a0 = __builtin_nontemporal_load(&s0[lane]);
    f32x4 b0 = __builtin_nontemporal_load(&s0[64 + lane]);
    f32x4 a1 = __builtin_nontemporal_load(&s1[lane]);
    f32x4 b1 = __builtin_nontemporal_load(&s1[64 + lane]);
    f32x4 a2 = __builtin_nontemporal_load(&s2[lane]);
    f32x4 b2 = __builtin_nontemporal_load(&s2[64 + lane]);
    f32x4 a3 = __builtin_nontemporal_load(&s3[lane]);
    f32x4 b3 = __builtin_nontemporal_load(&s3[64 + lane]);

    // In-lane argmax per task (first-index tie-break via strict >).
    float v0, v1, v2, v3; int i0, i1, i2, i3;
    task_argmax(a0, b0, lane, v0, i0);
    task_argmax(a1, b1, lane, v1, i1);
    task_argmax(a2, b2, lane, v2, i2);
    task_argmax(a3, b3, lane, v3, i3);

    // 64-lane butterfly reduce, 4 tasks interleaved for ILP; ties -> smaller k.
    #pragma unroll
    for (int mask = 1; mask < 64; mask <<= 1) {
        float o0 = __shfl_xor(v0, mask, 64);  int j0 = __shfl_xor(i0, mask, 64);
        float o1 = __shfl_xor(v1, mask, 64);  int j1 = __shfl_xor(i1, mask, 64);
        float o2 = __shfl_xor(v2, mask, 64);  int j2 = __shfl_xor(i2, mask, 64);
        float o3 = __shfl_xor(v3, mask, 64);  int j3 = __shfl_xor(i3, mask, 64);
        if (o0 > v0 || (o0 == v0 && j0 < i0)) { v0 = o0; i0 = j0; }
        if (o1 > v1 || (o1 == v1 && j1 < i1)) { v1 = o1; i1 = j1; }
        if (o2 > v2 || (o2 == v2 && j2 < i2)) { v2 = o2; i2 = j2; }
        if (o3 > v3 || (o3 == v3 && j3 < i3)) { v3 = o3; i3 = j3; }
    }

    // Four independent embedding-row gathers (emb is 1 MiB -> L2-resident).
    const int m0 = (t0 + 0) & (MM - 1);
    const int m1 = (t0 + 1) & (MM - 1);
    const int m2 = (t0 + 2) & (MM - 1);
    const int m3 = (t0 + 3) & (MM - 1);
    float e0 = emb[((size_t)m0 * KK + (size_t)i0) * DD + lane];
    float e1 = emb[((size_t)m1 * KK + (size_t)i1) * DD + lane];
    float e2 = emb[((size_t)m2 * KK + (size_t)i2) * DD + lane];
    float e3 = emb[((size_t)m3 * KK + (size_t)i3) * DD + lane];

    const size_t q0 = (size_t)t0 * DD + lane;
    __builtin_nontemporal_store(e0, &out[q0]);                     // quantized
    __builtin_nontemporal_store(e1, &out[q0 + DD]);
    __builtin_nontemporal_store(e2, &out[q0 + 2 * DD]);
    __builtin_nontemporal_store(e3, &out[q0 + 3 * DD]);
    __builtin_nontemporal_store(e0, &out[8388608 + q0]);           // quantized_stack
    __builtin_nontemporal_store(e1, &out[8388608 + q0 + DD]);
    __builtin_nontemporal_store(e2, &out[8388608 + q0 + 2 * DD]);
    __builtin_nontemporal_store(e3, &out[8388608 + q0 + 3 * DD]);

    // encoding_indices: lanes 0..3 write four contiguous floats.
    int myi = (lane == 0) ? i0 : (lane == 1) ? i1 : (lane == 2) ? i2 : i3;
    if (lane < 4)
        out[16777216 + (size_t)t0 + lane] = (float)myi;
}

extern "C" void kernel_launch(void* const* d_in, const int* in_sizes, int n_in,
                              void* d_out, int out_size, void* d_ws, size_t ws_size,
                              hipStream_t stream) {
    const float* logits = (const float*)d_in[0];
    const float* emb    = (const float*)d_in[1];
    float* out          = (float*)d_out;

    // N*M = 131072 tasks, 4 per wave, 4 waves per block -> 8192 blocks
    hardem_fwd<<<8192, 256, 0, stream>>>(logits, emb, out);
}